// Round 9
// baseline (559.321 us; speedup 1.0000x reference)
//
#include <hip/hip_runtime.h>

#define NB   4
#define NN1  8192
#define TT   15
#define NN2  4096
#define KCH  12
#define GG1  64
#define GG2  32
#define NCLS 6
#define EE1  131072
#define EE2  65536

typedef __attribute__((ext_vector_type(8))) short bf16x8;
typedef __attribute__((ext_vector_type(4))) float f32x4;

__device__ inline short f2bf(float f) {
    unsigned u = __builtin_bit_cast(unsigned, f);
    u += 0x7FFFu + ((u >> 16) & 1u);   // RNE
    return (short)(u >> 16);
}
__device__ inline bf16x8 cvt8(float4 a, float4 b) {
    bf16x8 r;
    r[0] = f2bf(a.x); r[1] = f2bf(a.y); r[2] = f2bf(a.z); r[3] = f2bf(a.w);
    r[4] = f2bf(b.x); r[5] = f2bf(b.y); r[6] = f2bf(b.z); r[7] = f2bf(b.w);
    return r;
}

// ---------------- degree + histogram ----------------
__global__ void k_deg_hist(const int* __restrict__ ei, const float* __restrict__ w,
                           float* __restrict__ deg, int* __restrict__ cnt, int E) {
    int e = blockIdx.x * 256 + threadIdx.x;
    if (e < E) {
        int d = ei[E + e];
        atomicAdd(&deg[d], w[e]);
        atomicAdd(&cnt[d], 1);
    }
}

// ---------------- exclusive scan (single block) ----------------
template <int N>
__global__ __launch_bounds__(1024) void k_scan(const int* __restrict__ cnt,
                                               int* __restrict__ offs, int* __restrict__ cur) {
    constexpr int PER = N / 1024;
    __shared__ int part[1024];
    int t = threadIdx.x;
    int loc[PER];
    int s = 0;
#pragma unroll
    for (int i = 0; i < PER; ++i) { loc[i] = s; s += cnt[t * PER + i]; }
    part[t] = s;
    __syncthreads();
    for (int off = 1; off < 1024; off <<= 1) {
        int v = (t >= off) ? part[t - off] : 0;
        __syncthreads();
        part[t] += v;
        __syncthreads();
    }
    int pre = t ? part[t - 1] : 0;
#pragma unroll
    for (int i = 0; i < PER; ++i) { int v = pre + loc[i]; offs[t * PER + i] = v; cur[t * PER + i] = v; }
    if (t == 1023) offs[N] = part[1023];
}

// ---------------- CSR fill (norm computed inline) ----------------
__global__ void k_fill(const int* __restrict__ ei, const float* __restrict__ w,
                       const float* __restrict__ deg, int* __restrict__ cur,
                       int* __restrict__ csrc, float* __restrict__ cnrm, int E) {
    int e = blockIdx.x * 256 + threadIdx.x;
    if (e < E) {
        int s = ei[e], d = ei[E + e];
        float ds = deg[s], dd = deg[d];
        float is = ds > 0.f ? 1.f / sqrtf(ds) : 0.f;
        float id = dd > 0.f ? 1.f / sqrtf(dd) : 0.f;
        int p = atomicAdd(&cur[d], 1);
        csrc[p] = s;
        cnrm[p] = -w[e] * is * id;
    }
}

// ---------------- build h0 (pads zeroed) ----------------
__global__ void k_build_h0(const float* __restrict__ x, float* __restrict__ h0,
                           short* __restrict__ bf0) {
    int idx = blockIdx.x * 256 + threadIdx.x;
    if (idx < NN1 * 64) {
        int n = idx >> 6, r = idx & 63;
        float v = 0.f;
        if (r < 60) {
            int t = r >> 2, b = r & 3;
            v = x[(b * NN1 + n) * TT + t];
        }
        h0[idx] = v;
        bf0[(size_t)n * 768 + r] = f2bf(v);
    }
}

// ---------------- conv1 prop: 4 waves/block, wave=node, 4 edge slots ----------------
__global__ __launch_bounds__(256) void k_prop1(const float* __restrict__ hprev,
                                               const float* __restrict__ hprev2,
                                               float* __restrict__ hout, short* __restrict__ bfs,
                                               const int* __restrict__ offs,
                                               const int* __restrict__ csrc,
                                               const float* __restrict__ cnrm, int first) {
    int n = blockIdx.x * 4 + (threadIdx.x >> 6);
    int lane = threadIdx.x & 63;
    int es = lane >> 4, f4 = lane & 15;
    int e0 = offs[n], e1 = offs[n + 1];
    f32x4 acc = {0.f, 0.f, 0.f, 0.f};
    for (int e = e0 + es; e < e1; e += 4) {
        int s = csrc[e];
        float wv = cnrm[e];
        const float4 v = *(const float4*)(hprev + (size_t)s * 64 + f4 * 4);
        acc[0] = fmaf(wv, v.x, acc[0]);
        acc[1] = fmaf(wv, v.y, acc[1]);
        acc[2] = fmaf(wv, v.z, acc[2]);
        acc[3] = fmaf(wv, v.w, acc[3]);
    }
#pragma unroll
    for (int i = 0; i < 4; ++i) {
        acc[i] += __shfl_xor(acc[i], 16, 64);
        acc[i] += __shfl_xor(acc[i], 32, 64);
    }
    if (es == 0) {
        float4 t;
        if (first) {
            t = make_float4(acc[0], acc[1], acc[2], acc[3]);
        } else {
            float4 p = *(const float4*)(hprev2 + (size_t)n * 64 + f4 * 4);
            t = make_float4(2.f * acc[0] - p.x, 2.f * acc[1] - p.y,
                            2.f * acc[2] - p.z, 2.f * acc[3] - p.w);
        }
        *(float4*)(hout + (size_t)n * 64 + f4 * 4) = t;
        short4 s4;
        s4.x = f2bf(t.x); s4.y = f2bf(t.y); s4.z = f2bf(t.z); s4.w = f2bf(t.w);
        *(short4*)(bfs + (size_t)n * 768 + f4 * 4) = s4;
    }
}

// ---------------- conv2 prop: wave = node (64 lanes x float4 = full 256-f row) ----------------
__global__ __launch_bounds__(256) void k_prop2(const float* __restrict__ hprev,
                                               const float* __restrict__ hprev2,
                                               float* __restrict__ hout, short* __restrict__ bfs,
                                               const int* __restrict__ offs,
                                               const int* __restrict__ csrc,
                                               const float* __restrict__ cnrm, int first) {
    int n = blockIdx.x * 4 + (threadIdx.x >> 6);
    int lane = threadIdx.x & 63;
    int e0 = offs[n], e1 = offs[n + 1];
    f32x4 a0 = {0.f, 0.f, 0.f, 0.f}, a1 = {0.f, 0.f, 0.f, 0.f};
    int e = e0;
    for (; e + 1 < e1; e += 2) {
        int s0 = csrc[e], s1 = csrc[e + 1];
        float w0 = cnrm[e], w1 = cnrm[e + 1];
        float4 v0 = *(const float4*)(hprev + (size_t)s0 * 256 + lane * 4);
        float4 v1 = *(const float4*)(hprev + (size_t)s1 * 256 + lane * 4);
        a0[0] = fmaf(w0, v0.x, a0[0]); a0[1] = fmaf(w0, v0.y, a0[1]);
        a0[2] = fmaf(w0, v0.z, a0[2]); a0[3] = fmaf(w0, v0.w, a0[3]);
        a1[0] = fmaf(w1, v1.x, a1[0]); a1[1] = fmaf(w1, v1.y, a1[1]);
        a1[2] = fmaf(w1, v1.z, a1[2]); a1[3] = fmaf(w1, v1.w, a1[3]);
    }
    if (e < e1) {
        int s0 = csrc[e];
        float w0 = cnrm[e];
        float4 v0 = *(const float4*)(hprev + (size_t)s0 * 256 + lane * 4);
        a0[0] = fmaf(w0, v0.x, a0[0]); a0[1] = fmaf(w0, v0.y, a0[1]);
        a0[2] = fmaf(w0, v0.z, a0[2]); a0[3] = fmaf(w0, v0.w, a0[3]);
    }
    f32x4 s = a0 + a1;
    float4 tt;
    if (first) {
        tt = make_float4(s[0], s[1], s[2], s[3]);
    } else {
        float4 p = *(const float4*)(hprev2 + (size_t)n * 256 + lane * 4);
        tt = make_float4(2.f * s[0] - p.x, 2.f * s[1] - p.y,
                         2.f * s[2] - p.z, 2.f * s[3] - p.w);
    }
    *(float4*)(hout + (size_t)n * 256 + lane * 4) = tt;
    short4 s4;
    s4.x = f2bf(tt.x); s4.y = f2bf(tt.y); s4.z = f2bf(tt.z); s4.w = f2bf(tt.w);
    *(short4*)(bfs + (size_t)n * 3072 + lane * 4) = s4;
}

// ---------------- block-diagonal weights, stored TRANSPOSED [N][K] bf16 ----------------
__global__ void k_w1p(const float* __restrict__ W1, short* __restrict__ W1p) {
    int idx = blockIdx.x * 256 + threadIdx.x;   // 256 * 768
    if (idx < 256 * 768) {
        int j = idx / 768, d = idx - j * 768;
        int g = j >> 2, b = j & 3;
        int k = d >> 6, r = d & 63, t = r >> 2, bp = r & 3;
        float v = (b == bp && t < TT) ? W1[k * (TT * GG1) + t * GG1 + g] : 0.f;
        W1p[idx] = f2bf(v);
    }
}
__global__ void k_w2p(const float* __restrict__ W2, short* __restrict__ W2p) {
    int idx = blockIdx.x * 256 + threadIdx.x;   // 128 * 3072
    if (idx < 128 * 3072) {
        int j = idx / 3072, d = idx - j * 3072;
        int g = j >> 2, b = j & 3;
        int k = d >> 8, r = d & 255, G = r >> 2, bp = r & 3;
        float v = (b == bp) ? W2[k * (GG1 * GG2) + G * GG2 + g] : 0.f;
        W2p[idx] = f2bf(v);
    }
}

// ---------------- 64-tile MFMA GEMM (y1/y2), double-buffered, split-K ----------------
template <bool A_BF, bool Y1EPI>
__global__ __launch_bounds__(256) void k_gemm(const void* __restrict__ Ap, int lda,
                                              const short* __restrict__ Bp, int ldb,
                                              const float* __restrict__ bias,
                                              float* __restrict__ Cf, int ldc,
                                              short* __restrict__ yT,
                                              int Kc, size_t pstride) {
    __shared__ short As[2][64][64];
    __shared__ short Bs[2][64][64];
    int m0 = blockIdx.x * 64, j0 = blockIdx.y * 64;
    int z = blockIdx.z;
    int kbeg = z * Kc;
    float* C = Cf + (size_t)z * pstride;
    int t = threadIdx.x;
    int lane = t & 63, wid = t >> 6;
    int wm = (wid >> 1) * 32, wn = (wid & 1) * 32;
    int lc = lane & 15, kg = lane >> 4;
    int r4 = t >> 2, c4 = (t & 3) * 16;
    int swa = (r4 & 7) << 3;

    const float* apf = (const float*)Ap + (size_t)(m0 + r4) * lda + kbeg + (t & 3) * 4;
    const short* apb = (const short*)Ap + (size_t)(m0 + r4) * lda + kbeg + c4;
    const short* bp  = Bp + (size_t)(j0 + r4) * ldb + kbeg + c4;

    float4 af0, af1, af2, af3;
    bf16x8 ab0, ab1, bb0, bb1;

    auto load_tile = [&](int k0) {
        if (A_BF) {
            ab0 = *(const bf16x8*)(apb + k0);
            ab1 = *(const bf16x8*)(apb + k0 + 8);
        } else {
            af0 = *(const float4*)(apf + k0);
            af1 = *(const float4*)(apf + k0 + 16);
            af2 = *(const float4*)(apf + k0 + 32);
            af3 = *(const float4*)(apf + k0 + 48);
        }
        bb0 = *(const bf16x8*)(bp + k0);
        bb1 = *(const bf16x8*)(bp + k0 + 8);
    };
    auto write_tile = [&](int buf) {
        if (A_BF) {
            *(bf16x8*)&As[buf][r4][c4 ^ swa] = ab0;
            *(bf16x8*)&As[buf][r4][(c4 + 8) ^ swa] = ab1;
        } else {
            short4 s;
            s.x = f2bf(af0.x); s.y = f2bf(af0.y); s.z = f2bf(af0.z); s.w = f2bf(af0.w);
            *(short4*)&As[buf][r4][((t & 3) * 4) ^ swa] = s;
            s.x = f2bf(af1.x); s.y = f2bf(af1.y); s.z = f2bf(af1.z); s.w = f2bf(af1.w);
            *(short4*)&As[buf][r4][((t & 3) * 4 + 16) ^ swa] = s;
            s.x = f2bf(af2.x); s.y = f2bf(af2.y); s.z = f2bf(af2.z); s.w = f2bf(af2.w);
            *(short4*)&As[buf][r4][((t & 3) * 4 + 32) ^ swa] = s;
            s.x = f2bf(af3.x); s.y = f2bf(af3.y); s.z = f2bf(af3.z); s.w = f2bf(af3.w);
            *(short4*)&As[buf][r4][((t & 3) * 4 + 48) ^ swa] = s;
        }
        *(bf16x8*)&Bs[buf][r4][c4 ^ swa] = bb0;
        *(bf16x8*)&Bs[buf][r4][(c4 + 8) ^ swa] = bb1;
    };

    f32x4 acc[2][2] = {};
    const int NIT = Kc >> 6;
    load_tile(0);
    write_tile(0);
    __syncthreads();
    for (int it = 0; it < NIT; ++it) {
        int cur = it & 1;
        if (it + 1 < NIT) load_tile((it + 1) << 6);
#pragma unroll
        for (int ks = 0; ks < 2; ++ks) {
            int kk = ks * 32 + kg * 8;
            bf16x8 a[2], b[2];
#pragma unroll
            for (int mi = 0; mi < 2; ++mi) {
                int row = wm + mi * 16 + lc;
                a[mi] = *(bf16x8*)&As[cur][row][kk ^ ((row & 7) << 3)];
            }
#pragma unroll
            for (int ni = 0; ni < 2; ++ni) {
                int row = wn + ni * 16 + lc;
                b[ni] = *(bf16x8*)&Bs[cur][row][kk ^ ((row & 7) << 3)];
            }
#pragma unroll
            for (int mi = 0; mi < 2; ++mi)
#pragma unroll
                for (int ni = 0; ni < 2; ++ni)
                    acc[mi][ni] = __builtin_amdgcn_mfma_f32_16x16x32_bf16(a[mi], b[ni], acc[mi][ni], 0, 0, 0);
        }
        if (it + 1 < NIT) write_tile(cur ^ 1);
        __syncthreads();
    }

    if (Y1EPI) {
#pragma unroll
        for (int mi = 0; mi < 2; ++mi)
#pragma unroll
            for (int ni = 0; ni < 2; ++ni) {
                int col = j0 + wn + ni * 16 + lc;
                float bb = bias[col >> 2];
                int row = m0 + wm + mi * 16 + kg * 4;
                short4 s;
                s.x = f2bf(fmaxf(acc[mi][ni][0] + bb, 0.f));
                s.y = f2bf(fmaxf(acc[mi][ni][1] + bb, 0.f));
                s.z = f2bf(fmaxf(acc[mi][ni][2] + bb, 0.f));
                s.w = f2bf(fmaxf(acc[mi][ni][3] + bb, 0.f));
                *(short4*)(yT + (size_t)col * NN1 + row) = s;
            }
    } else {
#pragma unroll
        for (int mi = 0; mi < 2; ++mi)
#pragma unroll
            for (int ni = 0; ni < 2; ++ni)
#pragma unroll
                for (int r = 0; r < 4; ++r) {
                    int row = m0 + wm + mi * 16 + kg * 4 + r, col = j0 + wn + ni * 16 + lc;
                    C[(size_t)row * ldc + col] = acc[mi][ni][r];
                }
    }
}

// ---------------- 128x128-tile MFMA GEMM for bmap (fp32 A, bf16 B j-major) ----------------
// 4 waves (2x2), each owns 64x64 (4x4 16x16 frags). BK=64. LDS 64KB dbuf.
__global__ __launch_bounds__(256) void k_gemm128(const float* __restrict__ Ap,
                                                 const short* __restrict__ Bp,
                                                 float* __restrict__ Cf,
                                                 int Kc, size_t pstride) {
    __shared__ short As[2][128][64];
    __shared__ short Bs[2][128][64];
    int m0 = blockIdx.x * 128, j0 = blockIdx.y * 128;
    int z = blockIdx.z;
    int kbeg = z * Kc;
    float* C = Cf + (size_t)z * pstride;
    int t = threadIdx.x;
    int lane = t & 63, wid = t >> 6;
    int wr = (wid >> 1) * 64, wc = (wid & 1) * 64;
    int lc = lane & 15, kg = lane >> 4;
    int rs = t >> 1;               // stage row 0..127
    int hb = (t & 1) * 32;         // stage col half (elems)
    int swa = (rs & 7) << 3;

    const float* ap = Ap + (size_t)(m0 + rs) * NN1 + kbeg + hb;
    const short* bp = Bp + (size_t)(j0 + rs) * NN1 + kbeg + hb;

    float4 af[8];
    bf16x8 bb[4];
    auto load_tile = [&](int k0) {
#pragma unroll
        for (int q = 0; q < 8; ++q) af[q] = *(const float4*)(ap + k0 + q * 4);
#pragma unroll
        for (int q = 0; q < 4; ++q) bb[q] = *(const bf16x8*)(bp + k0 + q * 8);
    };
    auto write_tile = [&](int buf) {
#pragma unroll
        for (int q = 0; q < 4; ++q)
            *(bf16x8*)&As[buf][rs][(hb + q * 8) ^ swa] = cvt8(af[2 * q], af[2 * q + 1]);
#pragma unroll
        for (int q = 0; q < 4; ++q)
            *(bf16x8*)&Bs[buf][rs][(hb + q * 8) ^ swa] = bb[q];
    };

    f32x4 acc[4][4] = {};
    const int NIT = Kc >> 6;
    load_tile(0);
    write_tile(0);
    __syncthreads();
    for (int it = 0; it < NIT; ++it) {
        int cur = it & 1;
        if (it + 1 < NIT) load_tile((it + 1) << 6);   // issue early
#pragma unroll
        for (int ks = 0; ks < 2; ++ks) {
            int kk = ks * 32 + kg * 8;
            bf16x8 a[4], b[4];
#pragma unroll
            for (int mi = 0; mi < 4; ++mi) {
                int row = wr + mi * 16 + lc;
                a[mi] = *(bf16x8*)&As[cur][row][kk ^ ((row & 7) << 3)];
            }
#pragma unroll
            for (int ni = 0; ni < 4; ++ni) {
                int row = wc + ni * 16 + lc;
                b[ni] = *(bf16x8*)&Bs[cur][row][kk ^ ((row & 7) << 3)];
            }
#pragma unroll
            for (int mi = 0; mi < 4; ++mi)
#pragma unroll
                for (int ni = 0; ni < 4; ++ni)
                    acc[mi][ni] = __builtin_amdgcn_mfma_f32_16x16x32_bf16(a[mi], b[ni], acc[mi][ni], 0, 0, 0);
        }
        if (it + 1 < NIT) write_tile(cur ^ 1);        // write-late
        __syncthreads();
    }
#pragma unroll
    for (int mi = 0; mi < 4; ++mi)
#pragma unroll
        for (int ni = 0; ni < 4; ++ni)
#pragma unroll
            for (int r = 0; r < 4; ++r) {
                int row = m0 + wr + mi * 16 + kg * 4 + r;
                int col = j0 + wc + ni * 16 + lc;
                C[(size_t)row * 256 + col] = acc[mi][ni][r];
            }
}

// ---------------- split-K reduces ----------------
__global__ void k_red8(const float* __restrict__ part, float* __restrict__ Cf,
                       short* __restrict__ Cbf) {
    int i = blockIdx.x * 256 + threadIdx.x;          // over NN2*256/4
    if (i < NN2 * 64) {
        const float4* p = (const float4*)part + i;
        float4 s = p[0];
#pragma unroll
        for (int z = 1; z < 8; ++z) {
            float4 v = p[(size_t)z * NN2 * 64];
            s.x += v.x; s.y += v.y; s.z += v.z; s.w += v.w;
        }
        ((float4*)Cf)[i] = s;
        int n = i >> 6, col = (i & 63) * 4;
        short4 s4;
        s4.x = f2bf(s.x); s4.y = f2bf(s.y); s4.z = f2bf(s.z); s4.w = f2bf(s.w);
        *(short4*)(Cbf + (size_t)n * 3072 + col) = s4;
    }
}
__global__ void k_red4(const float* __restrict__ part, float* __restrict__ Cf) {
    int i = blockIdx.x * 256 + threadIdx.x;          // over NN2*128/4
    if (i < NN2 * 32) {
        const float4* p = (const float4*)part + i;
        float4 s = p[0];
#pragma unroll
        for (int z = 1; z < 4; ++z) {
            float4 v = p[(size_t)z * NN2 * 32];
            s.x += v.x; s.y += v.y; s.z += v.z; s.w += v.w;
        }
        ((float4*)Cf)[i] = s;
    }
}

// ---------------- fc partial ----------------
__global__ __launch_bounds__(256) void k_fc(const float* __restrict__ y2, const float* __restrict__ b2,
                                            const float* __restrict__ fcw, float* __restrict__ logits) {
    int qc = blockIdx.x >> 4, ch = blockIdx.x & 15;
    int q = qc / NCLS, c = qc % NCLS;
    const float* yp = y2 + (size_t)q * 131072 + ch * 8192;
    const float* wp = fcw + (size_t)c * 131072 + ch * 8192;
    int t = threadIdx.x;
    float acc = 0.f;
#pragma unroll
    for (int it = 0; it < 8; ++it) {
        int o = it * 1024 + t * 4;
        float4 yv = *(const float4*)(yp + o);
        float4 wv = *(const float4*)(wp + o);
        float bg = b2[((ch * 8192 + o) >> 2) & 31];
        acc += (yv.x + bg) * wv.x + (yv.y + bg) * wv.y + (yv.z + bg) * wv.z + (yv.w + bg) * wv.w;
    }
#pragma unroll
    for (int o = 32; o; o >>= 1) acc += __shfl_down(acc, o, 64);
    __shared__ float red[4];
    if ((t & 63) == 0) red[t >> 6] = acc;
    __syncthreads();
    if (t == 0) atomicAdd(&logits[qc], red[0] + red[1] + red[2] + red[3]);
}

__global__ void k_lsm(const float* __restrict__ logits, const float* __restrict__ fcb,
                      float* __restrict__ out) {
    int q = threadIdx.x;
    if (q < NB) {
        float v[NCLS];
#pragma unroll
        for (int c = 0; c < NCLS; ++c) v[c] = logits[q * NCLS + c] + fcb[c];
        float m = -1e30f;
#pragma unroll
        for (int c = 0; c < NCLS; ++c) m = fmaxf(m, v[c]);
        float s = 0.f;
#pragma unroll
        for (int c = 0; c < NCLS; ++c) s += expf(v[c] - m);
        float lse = m + logf(s);
#pragma unroll
        for (int c = 0; c < NCLS; ++c) out[q * NCLS + c] = v[c] - lse;
    }
}

extern "C" void kernel_launch(void* const* d_in, const int* in_sizes, int n_in,
                              void* d_out, int out_size, void* d_ws, size_t ws_size,
                              hipStream_t stream) {
    const float* x    = (const float*)d_in[0];
    const int*   ei1  = (const int*)d_in[1];
    const float* ew1  = (const float*)d_in[2];
    const int*   ei2  = (const int*)d_in[3];
    const float* ew2  = (const float*)d_in[4];
    const float* bmap = (const float*)d_in[5];
    const float* W1   = (const float*)d_in[6];
    const float* b1   = (const float*)d_in[7];
    const float* W2   = (const float*)d_in[8];
    const float* b2   = (const float*)d_in[9];
    const float* fcw  = (const float*)d_in[10];
    const float* fcb  = (const float*)d_in[11];
    float* out = (float*)d_out;

    char* w = (char*)d_ws;
    size_t o = 0;
    auto alloc = [&](size_t bytes) {
        char* p = w + o;
        o += (bytes + 255) & ~(size_t)255;
        return p;
    };
    float* deg1  = (float*)alloc(NN1 * 4);
    float* deg2  = (float*)alloc(NN2 * 4);
    int*   cnt1  = (int*)alloc(NN1 * 4);
    int*   cnt2  = (int*)alloc(NN2 * 4);
    int*   offs1 = (int*)alloc((NN1 + 1) * 4);
    int*   offs2 = (int*)alloc((NN2 + 1) * 4);
    int*   cur1  = (int*)alloc(NN1 * 4);
    int*   cur2  = (int*)alloc(NN2 * 4);
    int*   csrc1 = (int*)alloc(EE1 * 4);
    float* cnrm1 = (float*)alloc(EE1 * 4);
    int*   csrc2 = (int*)alloc(EE2 * 4);
    float* cnrm2 = (float*)alloc(EE2 * 4);
    float* R1a = (float*)alloc(NN1 * 64 * 4);
    float* R1b = (float*)alloc(NN1 * 64 * 4);
    float* R1c = (float*)alloc(NN1 * 64 * 4);
    short* T1bf = (short*)alloc((size_t)NN1 * 768 * 2);
    short* ybfT = (short*)alloc((size_t)256 * NN1 * 2);        // relu(y1+b1)^T bf16 [256][8192]
    float* R2a = (float*)alloc((size_t)NN2 * 256 * 4);
    float* R2b = (float*)alloc((size_t)NN2 * 256 * 4);
    float* R2c = (float*)alloc((size_t)NN2 * 256 * 4);
    short* T2bf = (short*)alloc((size_t)NN2 * 3072 * 2);
    float* y2  = (float*)alloc((size_t)NN2 * 128 * 4);
    short* W1p = (short*)alloc(256 * 768 * 2);
    short* W2p = (short*)alloc(128 * 3072 * 2);
    float* part8 = (float*)alloc((size_t)8 * NN2 * 256 * 4);   // 32 MB
    float* part4 = (float*)alloc((size_t)4 * NN2 * 128 * 4);   // 8 MB
    float* logits = (float*)alloc(256);

    // ---- CSR build ----
    hipMemsetAsync(deg1, 0, NN1 * 4, stream);
    hipMemsetAsync(deg2, 0, NN2 * 4, stream);
    hipMemsetAsync(cnt1, 0, NN1 * 4, stream);
    hipMemsetAsync(cnt2, 0, NN2 * 4, stream);
    hipMemsetAsync(logits, 0, 256, stream);
    k_deg_hist<<<EE1 / 256, 256, 0, stream>>>(ei1, ew1, deg1, cnt1, EE1);
    k_deg_hist<<<EE2 / 256, 256, 0, stream>>>(ei2, ew2, deg2, cnt2, EE2);
    k_scan<NN1><<<1, 1024, 0, stream>>>(cnt1, offs1, cur1);
    k_scan<NN2><<<1, 1024, 0, stream>>>(cnt2, offs2, cur2);
    k_fill<<<EE1 / 256, 256, 0, stream>>>(ei1, ew1, deg1, cur1, csrc1, cnrm1, EE1);
    k_fill<<<EE2 / 256, 256, 0, stream>>>(ei2, ew2, deg2, cur2, csrc2, cnrm2, EE2);

    // ---- weights ----
    k_w1p<<<(256 * 768) / 256, 256, 0, stream>>>(W1, W1p);
    k_w2p<<<(128 * 3072) / 256, 256, 0, stream>>>(W2, W2p);

    // ---- conv1: Cheb recursion ----
    k_build_h0<<<(NN1 * 64) / 256, 256, 0, stream>>>(x, R1a, T1bf);
    {
        float *Tm1 = R1a, *Tm2 = nullptr, *fr = R1b, *spare = R1c;
        for (int k = 1; k < KCH; ++k) {
            k_prop1<<<NN1 / 4, 256, 0, stream>>>(Tm1, k == 1 ? Tm1 : Tm2, fr,
                                                 T1bf + k * 64, offs1, csrc1, cnrm1, k == 1 ? 1 : 0);
            float* nf = (k == 1) ? spare : Tm2;
            Tm2 = Tm1; Tm1 = fr; fr = nf;
        }
    }
    // ybfT = relu(T1bf @ W1p^T + b1)^T bf16   (M=8192, N=256, K=768)
    {
        dim3 g(NN1 / 64, 256 / 64, 1);
        k_gemm<true, true><<<g, 256, 0, stream>>>(T1bf, 768, W1p, 768, b1,
                                                  nullptr, 0, ybfT, 768, 0);
    }
    // bmap GEMM split-K x8 (128x128 tile): part8[z] = bmap @ ybfT^T chunk
    {
        dim3 g(NN2 / 128, 256 / 128, 8);
        k_gemm128<<<g, 256, 0, stream>>>(bmap, ybfT, part8, 1024, (size_t)NN2 * 256);
        k_red8<<<(NN2 * 64 + 255) / 256, 256, 0, stream>>>(part8, R2a, T2bf);
    }
    // ---- conv2 ----
    {
        float *Tm1 = R2a, *Tm2 = nullptr, *fr = R2b, *spare = R2c;
        for (int k = 1; k < KCH; ++k) {
            k_prop2<<<NN2 / 4, 256, 0, stream>>>(Tm1, k == 1 ? Tm1 : Tm2, fr,
                                                 T2bf + k * 256, offs2, csrc2, cnrm2, k == 1 ? 1 : 0);
            float* nf = (k == 1) ? spare : Tm2;
            Tm2 = Tm1; Tm1 = fr; fr = nf;
        }
    }
    // y2 = T2bf @ W2p^T   (M=4096, N=128, K=3072) split-K x4
    {
        dim3 g(NN2 / 64, 128 / 64, 4);
        k_gemm<true, false><<<g, 256, 0, stream>>>(T2bf, 3072, W2p, 3072, nullptr,
                                                   part4, 128, nullptr, 768, (size_t)NN2 * 128);
        k_red4<<<(NN2 * 32 + 255) / 256, 256, 0, stream>>>(part4, y2);
    }

    // ---- fc + log_softmax ----
    k_fc<<<NB * NCLS * 16, 256, 0, stream>>>(y2, b2, fcw, logits);
    k_lsm<<<1, 64, 0, stream>>>(logits, fcb, out);
}

// Round 10
// 537.487 us; speedup vs baseline: 1.0406x; 1.0406x over previous
//
#include <hip/hip_runtime.h>

#define NB   4
#define NN1  8192
#define TT   15
#define NN2  4096
#define KCH  12
#define GG1  64
#define GG2  32
#define NCLS 6
#define EE1  131072
#define EE2  65536

typedef __attribute__((ext_vector_type(8))) short bf16x8;
typedef __attribute__((ext_vector_type(4))) float f32x4;

__device__ inline short f2bf(float f) {
    unsigned u = __builtin_bit_cast(unsigned, f);
    u += 0x7FFFu + ((u >> 16) & 1u);   // RNE
    return (short)(u >> 16);
}
__device__ inline bf16x8 cvt8(float4 a, float4 b) {
    bf16x8 r;
    r[0] = f2bf(a.x); r[1] = f2bf(a.y); r[2] = f2bf(a.z); r[3] = f2bf(a.w);
    r[4] = f2bf(b.x); r[5] = f2bf(b.y); r[6] = f2bf(b.z); r[7] = f2bf(b.w);
    return r;
}

// ---------------- degree + histogram ----------------
__global__ void k_deg_hist(const int* __restrict__ ei, const float* __restrict__ w,
                           float* __restrict__ deg, int* __restrict__ cnt, int E) {
    int e = blockIdx.x * 256 + threadIdx.x;
    if (e < E) {
        int d = ei[E + e];
        atomicAdd(&deg[d], w[e]);
        atomicAdd(&cnt[d], 1);
    }
}

// ---------------- exclusive scan (single block) ----------------
template <int N>
__global__ __launch_bounds__(1024) void k_scan(const int* __restrict__ cnt,
                                               int* __restrict__ offs, int* __restrict__ cur) {
    constexpr int PER = N / 1024;
    __shared__ int part[1024];
    int t = threadIdx.x;
    int loc[PER];
    int s = 0;
#pragma unroll
    for (int i = 0; i < PER; ++i) { loc[i] = s; s += cnt[t * PER + i]; }
    part[t] = s;
    __syncthreads();
    for (int off = 1; off < 1024; off <<= 1) {
        int v = (t >= off) ? part[t - off] : 0;
        __syncthreads();
        part[t] += v;
        __syncthreads();
    }
    int pre = t ? part[t - 1] : 0;
#pragma unroll
    for (int i = 0; i < PER; ++i) { int v = pre + loc[i]; offs[t * PER + i] = v; cur[t * PER + i] = v; }
    if (t == 1023) offs[N] = part[1023];
}

// ---------------- CSR fill (norm computed inline) ----------------
__global__ void k_fill(const int* __restrict__ ei, const float* __restrict__ w,
                       const float* __restrict__ deg, int* __restrict__ cur,
                       int* __restrict__ csrc, float* __restrict__ cnrm, int E) {
    int e = blockIdx.x * 256 + threadIdx.x;
    if (e < E) {
        int s = ei[e], d = ei[E + e];
        float ds = deg[s], dd = deg[d];
        float is = ds > 0.f ? 1.f / sqrtf(ds) : 0.f;
        float id = dd > 0.f ? 1.f / sqrtf(dd) : 0.f;
        int p = atomicAdd(&cur[d], 1);
        csrc[p] = s;
        cnrm[p] = -w[e] * is * id;
    }
}

// ---------------- build h0 (pads zeroed) ----------------
__global__ void k_build_h0(const float* __restrict__ x, float* __restrict__ h0,
                           short* __restrict__ bf0) {
    int idx = blockIdx.x * 256 + threadIdx.x;
    if (idx < NN1 * 64) {
        int n = idx >> 6, r = idx & 63;
        float v = 0.f;
        if (r < 60) {
            int t = r >> 2, b = r & 3;
            v = x[(b * NN1 + n) * TT + t];
        }
        h0[idx] = v;
        bf0[(size_t)n * 768 + r] = f2bf(v);
    }
}

// ---------------- conv1 prop: 4 waves/block, wave=node, 4 edge slots ----------------
__global__ __launch_bounds__(256) void k_prop1(const float* __restrict__ hprev,
                                               const float* __restrict__ hprev2,
                                               float* __restrict__ hout, short* __restrict__ bfs,
                                               const int* __restrict__ offs,
                                               const int* __restrict__ csrc,
                                               const float* __restrict__ cnrm, int first) {
    int n = blockIdx.x * 4 + (threadIdx.x >> 6);
    int lane = threadIdx.x & 63;
    int es = lane >> 4, f4 = lane & 15;
    int e0 = offs[n], e1 = offs[n + 1];
    f32x4 acc = {0.f, 0.f, 0.f, 0.f};
    for (int e = e0 + es; e < e1; e += 4) {
        int s = csrc[e];
        float wv = cnrm[e];
        const float4 v = *(const float4*)(hprev + (size_t)s * 64 + f4 * 4);
        acc[0] = fmaf(wv, v.x, acc[0]);
        acc[1] = fmaf(wv, v.y, acc[1]);
        acc[2] = fmaf(wv, v.z, acc[2]);
        acc[3] = fmaf(wv, v.w, acc[3]);
    }
#pragma unroll
    for (int i = 0; i < 4; ++i) {
        acc[i] += __shfl_xor(acc[i], 16, 64);
        acc[i] += __shfl_xor(acc[i], 32, 64);
    }
    if (es == 0) {
        float4 t;
        if (first) {
            t = make_float4(acc[0], acc[1], acc[2], acc[3]);
        } else {
            float4 p = *(const float4*)(hprev2 + (size_t)n * 64 + f4 * 4);
            t = make_float4(2.f * acc[0] - p.x, 2.f * acc[1] - p.y,
                            2.f * acc[2] - p.z, 2.f * acc[3] - p.w);
        }
        *(float4*)(hout + (size_t)n * 64 + f4 * 4) = t;
        short4 s4;
        s4.x = f2bf(t.x); s4.y = f2bf(t.y); s4.z = f2bf(t.z); s4.w = f2bf(t.w);
        *(short4*)(bfs + (size_t)n * 768 + f4 * 4) = s4;
    }
}

// ---------------- conv2 prop: wave = node, 4-deep edge ILP ----------------
__global__ __launch_bounds__(256) void k_prop2(const float* __restrict__ hprev,
                                               const float* __restrict__ hprev2,
                                               float* __restrict__ hout, short* __restrict__ bfs,
                                               const int* __restrict__ offs,
                                               const int* __restrict__ csrc,
                                               const float* __restrict__ cnrm, int first) {
    int n = blockIdx.x * 4 + (threadIdx.x >> 6);
    int lane = threadIdx.x & 63;
    int e0 = offs[n], e1 = offs[n + 1];
    f32x4 a0 = {0.f, 0.f, 0.f, 0.f}, a1 = a0, a2 = a0, a3 = a0;
    int e = e0;
    for (; e + 3 < e1; e += 4) {
        int s0 = csrc[e], s1 = csrc[e + 1], s2 = csrc[e + 2], s3 = csrc[e + 3];
        float w0 = cnrm[e], w1 = cnrm[e + 1], w2 = cnrm[e + 2], w3 = cnrm[e + 3];
        float4 v0 = *(const float4*)(hprev + (size_t)s0 * 256 + lane * 4);
        float4 v1 = *(const float4*)(hprev + (size_t)s1 * 256 + lane * 4);
        float4 v2 = *(const float4*)(hprev + (size_t)s2 * 256 + lane * 4);
        float4 v3 = *(const float4*)(hprev + (size_t)s3 * 256 + lane * 4);
        a0[0] = fmaf(w0, v0.x, a0[0]); a0[1] = fmaf(w0, v0.y, a0[1]);
        a0[2] = fmaf(w0, v0.z, a0[2]); a0[3] = fmaf(w0, v0.w, a0[3]);
        a1[0] = fmaf(w1, v1.x, a1[0]); a1[1] = fmaf(w1, v1.y, a1[1]);
        a1[2] = fmaf(w1, v1.z, a1[2]); a1[3] = fmaf(w1, v1.w, a1[3]);
        a2[0] = fmaf(w2, v2.x, a2[0]); a2[1] = fmaf(w2, v2.y, a2[1]);
        a2[2] = fmaf(w2, v2.z, a2[2]); a2[3] = fmaf(w2, v2.w, a2[3]);
        a3[0] = fmaf(w3, v3.x, a3[0]); a3[1] = fmaf(w3, v3.y, a3[1]);
        a3[2] = fmaf(w3, v3.z, a3[2]); a3[3] = fmaf(w3, v3.w, a3[3]);
    }
    for (; e < e1; ++e) {
        int s0 = csrc[e];
        float w0 = cnrm[e];
        float4 v0 = *(const float4*)(hprev + (size_t)s0 * 256 + lane * 4);
        a0[0] = fmaf(w0, v0.x, a0[0]); a0[1] = fmaf(w0, v0.y, a0[1]);
        a0[2] = fmaf(w0, v0.z, a0[2]); a0[3] = fmaf(w0, v0.w, a0[3]);
    }
    f32x4 s = (a0 + a1) + (a2 + a3);
    float4 tt;
    if (first) {
        tt = make_float4(s[0], s[1], s[2], s[3]);
    } else {
        float4 p = *(const float4*)(hprev2 + (size_t)n * 256 + lane * 4);
        tt = make_float4(2.f * s[0] - p.x, 2.f * s[1] - p.y,
                         2.f * s[2] - p.z, 2.f * s[3] - p.w);
    }
    *(float4*)(hout + (size_t)n * 256 + lane * 4) = tt;
    short4 s4;
    s4.x = f2bf(tt.x); s4.y = f2bf(tt.y); s4.z = f2bf(tt.z); s4.w = f2bf(tt.w);
    *(short4*)(bfs + (size_t)n * 3072 + lane * 4) = s4;
}

// ---------------- block-diagonal weights, stored TRANSPOSED [N][K] bf16 ----------------
__global__ void k_w1p(const float* __restrict__ W1, short* __restrict__ W1p) {
    int idx = blockIdx.x * 256 + threadIdx.x;   // 256 * 768
    if (idx < 256 * 768) {
        int j = idx / 768, d = idx - j * 768;
        int g = j >> 2, b = j & 3;
        int k = d >> 6, r = d & 63, t = r >> 2, bp = r & 3;
        float v = (b == bp && t < TT) ? W1[k * (TT * GG1) + t * GG1 + g] : 0.f;
        W1p[idx] = f2bf(v);
    }
}
__global__ void k_w2p(const float* __restrict__ W2, short* __restrict__ W2p) {
    int idx = blockIdx.x * 256 + threadIdx.x;   // 128 * 3072
    if (idx < 128 * 3072) {
        int j = idx / 3072, d = idx - j * 3072;
        int g = j >> 2, b = j & 3;
        int k = d >> 8, r = d & 255, G = r >> 2, bp = r & 3;
        float v = (b == bp) ? W2[k * (GG1 * GG2) + G * GG2 + g] : 0.f;
        W2p[idx] = f2bf(v);
    }
}

// ---------------- 64-tile MFMA GEMM (y1/y2), dbuf, split-K, row-contiguous staging ----------------
template <bool A_BF, bool Y1EPI>
__global__ __launch_bounds__(256) void k_gemm(const void* __restrict__ Ap, int lda,
                                              const short* __restrict__ Bp, int ldb,
                                              const float* __restrict__ bias,
                                              float* __restrict__ Cf, int ldc,
                                              short* __restrict__ yT,
                                              int Kc, size_t pstride) {
    __shared__ short As[2][64][64];
    __shared__ short Bs[2][64][64];
    int m0 = blockIdx.x * 64, j0 = blockIdx.y * 64;
    int z = blockIdx.z;
    int kbeg = z * Kc;
    float* C = Cf + (size_t)z * pstride;
    int t = threadIdx.x;
    int lane = t & 63, wid = t >> 6;
    int wm = (wid >> 1) * 32, wn = (wid & 1) * 32;
    int lc = lane & 15, kg = lane >> 4;
    int srow = t >> 3;            // 0..31 (row within tile; +32 per q)
    int scol = (t & 7) * 8;       // 0..56 (8 elems = 16B, row-contiguous across 8 threads)

    const float* apf = (const float*)Ap + (size_t)(m0 + srow) * lda + kbeg + scol;
    const short* apb = (const short*)Ap + (size_t)(m0 + srow) * lda + kbeg + scol;
    const short* bp  = Bp + (size_t)(j0 + srow) * ldb + kbeg + scol;

    float4 afa[2], afb[2];
    bf16x8 ab[2], bb[2];

    auto load_tile = [&](int k0) {
#pragma unroll
        for (int q = 0; q < 2; ++q) {
            if (A_BF) {
                ab[q] = *(const bf16x8*)(apb + k0 + (size_t)(q * 32) * lda);
            } else {
                afa[q] = *(const float4*)(apf + k0 + (size_t)(q * 32) * lda);
                afb[q] = *(const float4*)(apf + k0 + (size_t)(q * 32) * lda + 4);
            }
            bb[q] = *(const bf16x8*)(bp + k0 + (size_t)(q * 32) * ldb);
        }
    };
    auto write_tile = [&](int buf) {
#pragma unroll
        for (int q = 0; q < 2; ++q) {
            int r = srow + 32 * q;
            int sw = (r & 7) << 3;
            if (A_BF) *(bf16x8*)&As[buf][r][scol ^ sw] = ab[q];
            else      *(bf16x8*)&As[buf][r][scol ^ sw] = cvt8(afa[q], afb[q]);
            *(bf16x8*)&Bs[buf][r][scol ^ sw] = bb[q];
        }
    };

    f32x4 acc[2][2] = {};
    const int NIT = Kc >> 6;
    load_tile(0);
    write_tile(0);
    __syncthreads();
    for (int it = 0; it < NIT; ++it) {
        int cur = it & 1;
        if (it + 1 < NIT) load_tile((it + 1) << 6);   // issue early; waitcnt lands after MFMA
#pragma unroll
        for (int ks = 0; ks < 2; ++ks) {
            int kk = ks * 32 + kg * 8;
            bf16x8 a[2], b[2];
#pragma unroll
            for (int mi = 0; mi < 2; ++mi) {
                int row = wm + mi * 16 + lc;
                a[mi] = *(bf16x8*)&As[cur][row][kk ^ ((row & 7) << 3)];
            }
#pragma unroll
            for (int ni = 0; ni < 2; ++ni) {
                int row = wn + ni * 16 + lc;
                b[ni] = *(bf16x8*)&Bs[cur][row][kk ^ ((row & 7) << 3)];
            }
#pragma unroll
            for (int mi = 0; mi < 2; ++mi)
#pragma unroll
                for (int ni = 0; ni < 2; ++ni)
                    acc[mi][ni] = __builtin_amdgcn_mfma_f32_16x16x32_bf16(a[mi], b[ni], acc[mi][ni], 0, 0, 0);
        }
        if (it + 1 < NIT) write_tile(cur ^ 1);        // write-late (other buffer)
        __syncthreads();
    }

    if (Y1EPI) {
#pragma unroll
        for (int mi = 0; mi < 2; ++mi)
#pragma unroll
            for (int ni = 0; ni < 2; ++ni) {
                int col = j0 + wn + ni * 16 + lc;
                float bb2 = bias[col >> 2];
                int row = m0 + wm + mi * 16 + kg * 4;
                short4 s;
                s.x = f2bf(fmaxf(acc[mi][ni][0] + bb2, 0.f));
                s.y = f2bf(fmaxf(acc[mi][ni][1] + bb2, 0.f));
                s.z = f2bf(fmaxf(acc[mi][ni][2] + bb2, 0.f));
                s.w = f2bf(fmaxf(acc[mi][ni][3] + bb2, 0.f));
                *(short4*)(yT + (size_t)col * NN1 + row) = s;
            }
    } else {
#pragma unroll
        for (int mi = 0; mi < 2; ++mi)
#pragma unroll
            for (int ni = 0; ni < 2; ++ni)
#pragma unroll
                for (int r = 0; r < 4; ++r) {
                    int row = m0 + wm + mi * 16 + kg * 4 + r, col = j0 + wn + ni * 16 + lc;
                    C[(size_t)row * ldc + col] = acc[mi][ni][r];
                }
    }
}

// ---------------- 128x128-tile MFMA GEMM for bmap, row-contiguous staging ----------------
// 4 waves (2x2), each owns 64x64 (4x4 16x16 frags). BK=64. LDS 64KB dbuf.
__global__ __launch_bounds__(256) void k_gemm128(const float* __restrict__ Ap,
                                                 const short* __restrict__ Bp,
                                                 float* __restrict__ Cf,
                                                 int Kc, size_t pstride) {
    __shared__ short As[2][128][64];
    __shared__ short Bs[2][128][64];
    int m0 = blockIdx.x * 128, j0 = blockIdx.y * 128;
    int z = blockIdx.z;
    int kbeg = z * Kc;
    float* C = Cf + (size_t)z * pstride;
    int t = threadIdx.x;
    int lane = t & 63, wid = t >> 6;
    int wr = (wid >> 1) * 64, wc = (wid & 1) * 64;
    int lc = lane & 15, kg = lane >> 4;
    int arow = t >> 4;            // 0..15 (+16 per q); 16 thr x 16B = full 256B fp32 row
    int acol = (t & 15) * 4;      // 0..60
    int brow = t >> 3;            // 0..31 (+32 per q); 8 thr x 16B = full 128B bf16 row
    int bcol = (t & 7) * 8;       // 0..56

    const float* ap = Ap + (size_t)(m0 + arow) * NN1 + kbeg + acol;
    const short* bp = Bp + (size_t)(j0 + brow) * NN1 + kbeg + bcol;

    float4 af[8];
    bf16x8 bb[4];
    auto load_tile = [&](int k0) {
#pragma unroll
        for (int q = 0; q < 8; ++q) af[q] = *(const float4*)(ap + k0 + (size_t)(q * 16) * NN1);
#pragma unroll
        for (int q = 0; q < 4; ++q) bb[q] = *(const bf16x8*)(bp + k0 + (size_t)(q * 32) * NN1);
    };
    auto write_tile = [&](int buf) {
#pragma unroll
        for (int q = 0; q < 8; ++q) {
            int r = arow + 16 * q;
            int sw = (r & 7) << 3;
            short4 s;
            s.x = f2bf(af[q].x); s.y = f2bf(af[q].y); s.z = f2bf(af[q].z); s.w = f2bf(af[q].w);
            *(short4*)&As[buf][r][acol ^ sw] = s;
        }
#pragma unroll
        for (int q = 0; q < 4; ++q) {
            int r = brow + 32 * q;
            *(bf16x8*)&Bs[buf][r][bcol ^ ((r & 7) << 3)] = bb[q];
        }
    };

    f32x4 acc[4][4] = {};
    const int NIT = Kc >> 6;
    load_tile(0);
    write_tile(0);
    __syncthreads();
    for (int it = 0; it < NIT; ++it) {
        int cur = it & 1;
        if (it + 1 < NIT) load_tile((it + 1) << 6);   // issue early
#pragma unroll
        for (int ks = 0; ks < 2; ++ks) {
            int kk = ks * 32 + kg * 8;
            bf16x8 a[4], b[4];
#pragma unroll
            for (int mi = 0; mi < 4; ++mi) {
                int row = wr + mi * 16 + lc;
                a[mi] = *(bf16x8*)&As[cur][row][kk ^ ((row & 7) << 3)];
            }
#pragma unroll
            for (int ni = 0; ni < 4; ++ni) {
                int row = wc + ni * 16 + lc;
                b[ni] = *(bf16x8*)&Bs[cur][row][kk ^ ((row & 7) << 3)];
            }
#pragma unroll
            for (int mi = 0; mi < 4; ++mi)
#pragma unroll
                for (int ni = 0; ni < 4; ++ni)
                    acc[mi][ni] = __builtin_amdgcn_mfma_f32_16x16x32_bf16(a[mi], b[ni], acc[mi][ni], 0, 0, 0);
        }
        if (it + 1 < NIT) write_tile(cur ^ 1);        // write-late
        __syncthreads();
    }
#pragma unroll
    for (int mi = 0; mi < 4; ++mi)
#pragma unroll
        for (int ni = 0; ni < 4; ++ni)
#pragma unroll
            for (int r = 0; r < 4; ++r) {
                int row = m0 + wr + mi * 16 + kg * 4 + r;
                int col = j0 + wc + ni * 16 + lc;
                C[(size_t)row * 256 + col] = acc[mi][ni][r];
            }
}

// ---------------- split-K reduces ----------------
__global__ void k_red8(const float* __restrict__ part, float* __restrict__ Cf,
                       short* __restrict__ Cbf) {
    int i = blockIdx.x * 256 + threadIdx.x;          // over NN2*256/4
    if (i < NN2 * 64) {
        const float4* p = (const float4*)part + i;
        float4 s = p[0];
#pragma unroll
        for (int z = 1; z < 8; ++z) {
            float4 v = p[(size_t)z * NN2 * 64];
            s.x += v.x; s.y += v.y; s.z += v.z; s.w += v.w;
        }
        ((float4*)Cf)[i] = s;
        int n = i >> 6, col = (i & 63) * 4;
        short4 s4;
        s4.x = f2bf(s.x); s4.y = f2bf(s.y); s4.z = f2bf(s.z); s4.w = f2bf(s.w);
        *(short4*)(Cbf + (size_t)n * 3072 + col) = s4;
    }
}
__global__ void k_red4(const float* __restrict__ part, float* __restrict__ Cf) {
    int i = blockIdx.x * 256 + threadIdx.x;          // over NN2*128/4
    if (i < NN2 * 32) {
        const float4* p = (const float4*)part + i;
        float4 s = p[0];
#pragma unroll
        for (int z = 1; z < 4; ++z) {
            float4 v = p[(size_t)z * NN2 * 32];
            s.x += v.x; s.y += v.y; s.z += v.z; s.w += v.w;
        }
        ((float4*)Cf)[i] = s;
    }
}

// ---------------- fc partial ----------------
__global__ __launch_bounds__(256) void k_fc(const float* __restrict__ y2, const float* __restrict__ b2,
                                            const float* __restrict__ fcw, float* __restrict__ logits) {
    int qc = blockIdx.x >> 4, ch = blockIdx.x & 15;
    int q = qc / NCLS, c = qc % NCLS;
    const float* yp = y2 + (size_t)q * 131072 + ch * 8192;
    const float* wp = fcw + (size_t)c * 131072 + ch * 8192;
    int t = threadIdx.x;
    float acc = 0.f;
#pragma unroll
    for (int it = 0; it < 8; ++it) {
        int o = it * 1024 + t * 4;
        float4 yv = *(const float4*)(yp + o);
        float4 wv = *(const float4*)(wp + o);
        float bg = b2[((ch * 8192 + o) >> 2) & 31];
        acc += (yv.x + bg) * wv.x + (yv.y + bg) * wv.y + (yv.z + bg) * wv.z + (yv.w + bg) * wv.w;
    }
#pragma unroll
    for (int o = 32; o; o >>= 1) acc += __shfl_down(acc, o, 64);
    __shared__ float red[4];
    if ((t & 63) == 0) red[t >> 6] = acc;
    __syncthreads();
    if (t == 0) atomicAdd(&logits[qc], red[0] + red[1] + red[2] + red[3]);
}

__global__ void k_lsm(const float* __restrict__ logits, const float* __restrict__ fcb,
                      float* __restrict__ out) {
    int q = threadIdx.x;
    if (q < NB) {
        float v[NCLS];
#pragma unroll
        for (int c = 0; c < NCLS; ++c) v[c] = logits[q * NCLS + c] + fcb[c];
        float m = -1e30f;
#pragma unroll
        for (int c = 0; c < NCLS; ++c) m = fmaxf(m, v[c]);
        float s = 0.f;
#pragma unroll
        for (int c = 0; c < NCLS; ++c) s += expf(v[c] - m);
        float lse = m + logf(s);
#pragma unroll
        for (int c = 0; c < NCLS; ++c) out[q * NCLS + c] = v[c] - lse;
    }
}

extern "C" void kernel_launch(void* const* d_in, const int* in_sizes, int n_in,
                              void* d_out, int out_size, void* d_ws, size_t ws_size,
                              hipStream_t stream) {
    const float* x    = (const float*)d_in[0];
    const int*   ei1  = (const int*)d_in[1];
    const float* ew1  = (const float*)d_in[2];
    const int*   ei2  = (const int*)d_in[3];
    const float* ew2  = (const float*)d_in[4];
    const float* bmap = (const float*)d_in[5];
    const float* W1   = (const float*)d_in[6];
    const float* b1   = (const float*)d_in[7];
    const float* W2   = (const float*)d_in[8];
    const float* b2   = (const float*)d_in[9];
    const float* fcw  = (const float*)d_in[10];
    const float* fcb  = (const float*)d_in[11];
    float* out = (float*)d_out;

    char* w = (char*)d_ws;
    size_t o = 0;
    auto alloc = [&](size_t bytes) {
        char* p = w + o;
        o += (bytes + 255) & ~(size_t)255;
        return p;
    };
    float* deg1  = (float*)alloc(NN1 * 4);
    float* deg2  = (float*)alloc(NN2 * 4);
    int*   cnt1  = (int*)alloc(NN1 * 4);
    int*   cnt2  = (int*)alloc(NN2 * 4);
    int*   offs1 = (int*)alloc((NN1 + 1) * 4);
    int*   offs2 = (int*)alloc((NN2 + 1) * 4);
    int*   cur1  = (int*)alloc(NN1 * 4);
    int*   cur2  = (int*)alloc(NN2 * 4);
    int*   csrc1 = (int*)alloc(EE1 * 4);
    float* cnrm1 = (float*)alloc(EE1 * 4);
    int*   csrc2 = (int*)alloc(EE2 * 4);
    float* cnrm2 = (float*)alloc(EE2 * 4);
    float* R1a = (float*)alloc(NN1 * 64 * 4);
    float* R1b = (float*)alloc(NN1 * 64 * 4);
    float* R1c = (float*)alloc(NN1 * 64 * 4);
    short* T1bf = (short*)alloc((size_t)NN1 * 768 * 2);
    short* ybfT = (short*)alloc((size_t)256 * NN1 * 2);        // relu(y1+b1)^T bf16 [256][8192]
    float* R2a = (float*)alloc((size_t)NN2 * 256 * 4);
    float* R2b = (float*)alloc((size_t)NN2 * 256 * 4);
    float* R2c = (float*)alloc((size_t)NN2 * 256 * 4);
    short* T2bf = (short*)alloc((size_t)NN2 * 3072 * 2);
    float* y2  = (float*)alloc((size_t)NN2 * 128 * 4);
    short* W1p = (short*)alloc(256 * 768 * 2);
    short* W2p = (short*)alloc(128 * 3072 * 2);
    float* part8 = (float*)alloc((size_t)8 * NN2 * 256 * 4);   // 32 MB
    float* part4 = (float*)alloc((size_t)4 * NN2 * 128 * 4);   // 8 MB
    float* logits = (float*)alloc(256);

    // ---- CSR build ----
    hipMemsetAsync(deg1, 0, NN1 * 4, stream);
    hipMemsetAsync(deg2, 0, NN2 * 4, stream);
    hipMemsetAsync(cnt1, 0, NN1 * 4, stream);
    hipMemsetAsync(cnt2, 0, NN2 * 4, stream);
    hipMemsetAsync(logits, 0, 256, stream);
    k_deg_hist<<<EE1 / 256, 256, 0, stream>>>(ei1, ew1, deg1, cnt1, EE1);
    k_deg_hist<<<EE2 / 256, 256, 0, stream>>>(ei2, ew2, deg2, cnt2, EE2);
    k_scan<NN1><<<1, 1024, 0, stream>>>(cnt1, offs1, cur1);
    k_scan<NN2><<<1, 1024, 0, stream>>>(cnt2, offs2, cur2);
    k_fill<<<EE1 / 256, 256, 0, stream>>>(ei1, ew1, deg1, cur1, csrc1, cnrm1, EE1);
    k_fill<<<EE2 / 256, 256, 0, stream>>>(ei2, ew2, deg2, cur2, csrc2, cnrm2, EE2);

    // ---- weights ----
    k_w1p<<<(256 * 768) / 256, 256, 0, stream>>>(W1, W1p);
    k_w2p<<<(128 * 3072) / 256, 256, 0, stream>>>(W2, W2p);

    // ---- conv1: Cheb recursion ----
    k_build_h0<<<(NN1 * 64) / 256, 256, 0, stream>>>(x, R1a, T1bf);
    {
        float *Tm1 = R1a, *Tm2 = nullptr, *fr = R1b, *spare = R1c;
        for (int k = 1; k < KCH; ++k) {
            k_prop1<<<NN1 / 4, 256, 0, stream>>>(Tm1, k == 1 ? Tm1 : Tm2, fr,
                                                 T1bf + k * 64, offs1, csrc1, cnrm1, k == 1 ? 1 : 0);
            float* nf = (k == 1) ? spare : Tm2;
            Tm2 = Tm1; Tm1 = fr; fr = nf;
        }
    }
    // ybfT = relu(T1bf @ W1p^T + b1)^T bf16   (M=8192, N=256, K=768)
    {
        dim3 g(NN1 / 64, 256 / 64, 1);
        k_gemm<true, true><<<g, 256, 0, stream>>>(T1bf, 768, W1p, 768, b1,
                                                  nullptr, 0, ybfT, 768, 0);
    }
    // bmap GEMM split-K x8 (128x128 tile): part8[z] = bmap @ ybfT^T chunk
    {
        dim3 g(NN2 / 128, 256 / 128, 8);
        k_gemm128<<<g, 256, 0, stream>>>(bmap, ybfT, part8, 1024, (size_t)NN2 * 256);
        k_red8<<<(NN2 * 64 + 255) / 256, 256, 0, stream>>>(part8, R2a, T2bf);
    }
    // ---- conv2 ----
    {
        float *Tm1 = R2a, *Tm2 = nullptr, *fr = R2b, *spare = R2c;
        for (int k = 1; k < KCH; ++k) {
            k_prop2<<<NN2 / 4, 256, 0, stream>>>(Tm1, k == 1 ? Tm1 : Tm2, fr,
                                                 T2bf + k * 256, offs2, csrc2, cnrm2, k == 1 ? 1 : 0);
            float* nf = (k == 1) ? spare : Tm2;
            Tm2 = Tm1; Tm1 = fr; fr = nf;
        }
    }
    // y2 = T2bf @ W2p^T   (M=4096, N=128, K=3072) split-K x4
    {
        dim3 g(NN2 / 64, 128 / 64, 4);
        k_gemm<true, false><<<g, 256, 0, stream>>>(T2bf, 3072, W2p, 3072, nullptr,
                                                   part4, 128, nullptr, 768, (size_t)NN2 * 128);
        k_red4<<<(NN2 * 32 + 255) / 256, 256, 0, stream>>>(part4, y2);
    }

    // ---- fc + log_softmax ----
    k_fc<<<NB * NCLS * 16, 256, 0, stream>>>(y2, b2, fcw, logits);
    k_lsm<<<1, 64, 0, stream>>>(logits, fcb, out);
}